// Round 11
// baseline (210.390 us; speedup 1.0000x reference)
//
#include <hip/hip_runtime.h>
#include <hip/hip_bf16.h>

#define NHEAD 8
#define SEQ   2048
#define HD    64
#define EMB   512
#define NTYPE 10
#define JSPLIT 4

#define QKV_NT (3 * EMB / 64)              // 24 n-tiles
#define QKV_MT (SEQ / 64)                  // 32 m-tiles
#define QKV_BLOCKS (QKV_NT * QKV_MT)       // 768
#define PACK_BLOCKS (SEQ * SEQ / 4 / 256)  // 4096
#define OPW_BLOCKS (EMB * EMB / 8 / 256)   // 128
#define PREP_BLOCKS (QKV_BLOCKS + PACK_BLOCKS + OPW_BLOCKS + 1)

#define QSCALE 0.180336878f                // 0.125 * log2(e): exp2-domain softmax

typedef unsigned short u16;
typedef __attribute__((ext_vector_type(8))) short short8;
typedef __attribute__((ext_vector_type(4))) short short4v;
typedef __attribute__((ext_vector_type(4))) float float4v;

union F8 { short8 v; uint4 u4; u16 us[8]; };
union PB { uint2 u2; short4v s4; };

__device__ __forceinline__ float bf2f(u16 u){
  union { unsigned u; float f; } w; w.u = ((unsigned)u) << 16; return w.f;
}
__device__ __forceinline__ u16 f2bf(float f){
  union { float f; unsigned u; } w; w.f = f;
  unsigned u = w.u;
  u += 0x7fffu + ((u >> 16) & 1u);   // RNE
  return (u16)(u >> 16);
}
// HW v_cvt_pk_bf16_f32 (RNE)
__device__ __forceinline__ unsigned cvtpk(float lo, float hi){
  union { __hip_bfloat162 b; unsigned u; } w;
  w.b = __float22bfloat162_rn(float2{lo, hi});
  return w.u;
}
__device__ __forceinline__ uint4 pk8(float4 a, float4 b){
  uint4 p; p.x = cvtpk(a.x, a.y); p.y = cvtpk(a.z, a.w);
           p.z = cvtpk(b.x, b.y); p.w = cvtpk(b.z, b.w);
  return p;
}

// PV micro-op: ao += P(A-frag, regs) * V(B-frag, 4 bf16).
__device__ __forceinline__ void pv_mfma(float4v& ao, uint2 pa, uint2 vb){
#if __has_builtin(__builtin_amdgcn_mfma_f32_16x16x16bf16_1k)
  PB a; a.u2 = pa;
  PB b; b.u2 = vb;
  ao = __builtin_amdgcn_mfma_f32_16x16x16bf16_1k(a.s4, b.s4, ao, 0, 0, 0);
#else
  asm volatile("s_nop 1\n\tv_mfma_f32_16x16x16_bf16 %0, %1, %2, %0"
               : "+v"(ao) : "v"(pa), "v"(vb));
#endif
}

// ---------------------------------------------------------------- K1: QKV projection + eid pack + opw cvt + EK pad
// blocks [0,768): 64x64 GEMM, BK=64, reg-staged fp32->bf16, XCD-grouped (X owns 4 m-tiles).
// blocks [768, 4864): eid int32 -> u8 pack.
// blocks [4864, 4992): opw fp32 -> bf16.
// block 4992: EK -> bf16, zero-padded to 16 type rows.
__global__ __launch_bounds__(256) void fused_prep_gemm(
    const float* __restrict__ q, const float* __restrict__ k, const float* __restrict__ v,
    const float* __restrict__ ipw, const float* __restrict__ ipb, const int* __restrict__ eid,
    const float* __restrict__ opw, const float* __restrict__ ek,
    u16* __restrict__ Qs, u16* __restrict__ Kb, u16* __restrict__ Vb,
    unsigned* __restrict__ eidp, u16* __restrict__ opwb, u16* __restrict__ EKb)
{
  const int b = blockIdx.x;
  const int t = threadIdx.x;

  if (b >= QKV_BLOCKS) {
    if (b < QKV_BLOCKS + PACK_BLOCKS) {          // ---- eid pack
      const int i = (b - QKV_BLOCKS) * 256 + t;
      int4 vv = ((const int4*)eid)[i];
      eidp[i] = (unsigned)(vv.x & 0xff) | ((unsigned)(vv.y & 0xff) << 8) |
                ((unsigned)(vv.z & 0xff) << 16) | ((unsigned)(vv.w & 0xff) << 24);
    } else if (b < QKV_BLOCKS + PACK_BLOCKS + OPW_BLOCKS) {   // ---- opw -> bf16
      const int i = (b - QKV_BLOCKS - PACK_BLOCKS) * 256 + t;
      float4 a = *(const float4*)(opw + i * 8);
      float4 c = *(const float4*)(opw + i * 8 + 4);
      *(uint4*)(opwb + i * 8) = pk8(a, c);
    } else {                                     // ---- EK -> bf16, pad to 16 rows
      const int gi = t * 4;                      // 1024 = 16x64
      ushort4 pk;
      u16* pp = (u16*)&pk;
#pragma unroll
      for (int e = 0; e < 4; e++) {
        const int type = (gi + e) >> 6, d = (gi + e) & 63;
        pp[e] = f2bf(type < NTYPE ? ek[type * HD + d] : 0.f);
      }
      *(ushort4*)(EKb + gi) = pk;
    }
    return;
  }

  __shared__ u16 As[64][72];
  __shared__ u16 Bs[64][72];

  const int X = b & 7, jb = b >> 3;
  const int mt = X * 4 + (jb & 3), nt = jb >> 2;
  const int n0 = nt * 64, m0 = mt * 64;
  const int z = n0 >> 9;                       // 0=q,1=k,2=v
  const float* A = (z == 0) ? q : (z == 1) ? k : v;
  const float scale = (z == 0) ? QSCALE : 1.0f;

  const int w = t >> 6, lane = t & 63, lr = lane & 15, lg = lane >> 4;
  const int wm = w >> 1, wn = w & 1;
  const int srow = t >> 2, kb16 = (t & 3) * 16;

  float4v acc[2][2];
#pragma unroll
  for (int mi = 0; mi < 2; mi++)
#pragma unroll
    for (int ni = 0; ni < 2; ni++) acc[mi][ni] = (float4v){0.f, 0.f, 0.f, 0.f};

  const float* pa = A   + (size_t)(m0 + srow) * EMB + kb16;
  const float* pw = ipw + (size_t)(n0 + srow) * EMB + kb16;

  float4 a[4], bb[4];
#pragma unroll
  for (int j = 0; j < 4; j++) { a[j] = *(const float4*)(pa + j * 4); bb[j] = *(const float4*)(pw + j * 4); }

  for (int k0 = 0; k0 < EMB; k0 += 64) {
    *(uint4*)&As[srow][kb16]     = pk8(a[0], a[1]);
    *(uint4*)&As[srow][kb16 + 8] = pk8(a[2], a[3]);
    *(uint4*)&Bs[srow][kb16]     = pk8(bb[0], bb[1]);
    *(uint4*)&Bs[srow][kb16 + 8] = pk8(bb[2], bb[3]);
    __syncthreads();
    if (k0 + 64 < EMB) {                       // prefetch next K-tile
#pragma unroll
      for (int j = 0; j < 4; j++) {
        a[j]  = *(const float4*)(pa + k0 + 64 + j * 4);
        bb[j] = *(const float4*)(pw + k0 + 64 + j * 4);
      }
    }
    F8 af[2][2], bf_[2][2];
#pragma unroll
    for (int kc = 0; kc < 2; kc++) {
#pragma unroll
      for (int mi = 0; mi < 2; mi++)
        af[mi][kc].u4 = *(const uint4*)&As[wm * 32 + mi * 16 + lr][kc * 32 + lg * 8];
#pragma unroll
      for (int ni = 0; ni < 2; ni++)
        bf_[ni][kc].u4 = *(const uint4*)&Bs[wn * 32 + ni * 16 + lr][kc * 32 + lg * 8];
    }
#pragma unroll
    for (int kc = 0; kc < 2; kc++)
#pragma unroll
      for (int mi = 0; mi < 2; mi++)
#pragma unroll
        for (int ni = 0; ni < 2; ni++)
          acc[mi][ni] = __builtin_amdgcn_mfma_f32_16x16x32_bf16(af[mi][kc].v, bf_[ni][kc].v, acc[mi][ni], 0, 0, 0);
    __syncthreads();
  }

  u16* O = (z == 0) ? Qs : ((z == 1) ? Kb : Vb);
#pragma unroll
  for (int mi = 0; mi < 2; mi++) {
#pragma unroll
    for (int ni = 0; ni < 2; ni++) {
      const int n = n0 + wn * 32 + ni * 16 + lr;
      const int e = n & 511, h = e >> 6, d = e & 63;
      const float bias = ipb[n];
      const int mb = m0 + wm * 32 + mi * 16 + lg * 4;
      if (z < 2) {
#pragma unroll
        for (int r = 0; r < 4; r++)
          O[((size_t)h * SEQ + mb + r) * HD + d] = f2bf((acc[mi][ni][r] + bias) * scale);
      } else {
        ushort4 pk;
        pk.x = f2bf(acc[mi][ni][0] + bias); pk.y = f2bf(acc[mi][ni][1] + bias);
        pk.z = f2bf(acc[mi][ni][2] + bias); pk.w = f2bf(acc[mi][ni][3] + bias);
        *(ushort4*)(O + ((size_t)(h * HD + d)) * SEQ + mb) = pk;   // V^T layout [h][d][m]
      }
    }
  }
}

// ---------------------------------------------------------------- K2: BARRIER-FREE flash attention
// No K/V LDS staging: QK^T B-frags (16B) and PV V-frags (8B) read directly from
// global (L2-resident per XCD: head h == XCD X). Type scores via 2-MFMA trick
// (TS = mfma(EK_pad, Q), same swapped layout as QK^T) into a PER-WAVE LDS region
// -> zero __syncthreads in the whole kernel; waves fully independent.
// Softmax m/l in regs, exp2-domain; PV from register P-fragments (16x16x16 MFMA).
// grid 1024 = 32 i-tiles x 8 h x 4 z, XCD-grouped.
__global__ __launch_bounds__(256) void attn_kernel(
    const u16* __restrict__ Qs, const u16* __restrict__ Kb, const u16* __restrict__ Vb,
    const unsigned* __restrict__ eid32, const u16* __restrict__ EKb,
    u16* __restrict__ Upart, float* __restrict__ mpart, float* __restrict__ lpart)
{
  __shared__ float tsl[4][16][18];      // per-wave type scores [i-local][type], no barrier needed

  const int t = threadIdx.x;
  const int wave = t >> 6, lane = t & 63, lr = lane & 15, lg = lane >> 4;
  // XCD-grouped (bijective): X = b%8 owns (h,z) pairs [4X,4X+4) -> h == X
  const int bb_ = blockIdx.x;
  const int X = bb_ & 7, jj = bb_ >> 3;           // jj 0..127
  const int p = X * 4 + (jj >> 5);                // pair 0..31
  const int i0 = (jj & 31) * 64;
  const int h  = p >> 2;
  const int z  = p & 3;

  const int irow = i0 + wave * 16 + lr;           // this lane's Q row

  // Q fragments (B operand), held in regs
  F8 qf[2];
#pragma unroll
  for (int kc = 0; kc < 2; kc++)
    qf[kc].u4 = *(const uint4*)(Qs + ((size_t)h * SEQ + irow) * HD + kc * 32 + lg * 8);

  // type scores via MFMA: TS[i=lr][type=lg*4+r] (EK zero-padded to 16 rows)
  {
    float4v ts = (float4v){0.f, 0.f, 0.f, 0.f};
#pragma unroll
    for (int kc = 0; kc < 2; kc++) {
      F8 ekf; ekf.u4 = *(const uint4*)(EKb + lr * HD + kc * 32 + lg * 8);
      ts = __builtin_amdgcn_mfma_f32_16x16x32_bf16(ekf.v, qf[kc].v, ts, 0, 0, 0);
    }
    *(float2*)&tsl[wave][lr][lg * 4]     = float2{ts[0], ts[1]};
    *(float2*)&tsl[wave][lr][lg * 4 + 2] = float2{ts[2], ts[3]};
    // same-wave LDS RAW: compiler inserts lgkmcnt wait; no block barrier needed
  }

  float4v ao[4];                        // ao[db][rr] = O[i=lg*4+rr][d=db*16+lr]
#pragma unroll
  for (int d = 0; d < 4; d++) ao[d] = (float4v){0.f, 0.f, 0.f, 0.f};
  float m_i = -1e30f, l_i = 0.f;        // own-row (i = irow) softmax state

  const u16* kbase = Kb + (size_t)h * SEQ * HD;
  const u16* vbase = Vb + (size_t)h * HD * SEQ;
  const unsigned* erow = eid32 + (size_t)irow * (SEQ / 4);
  const int jbase = z * (SEQ / JSPLIT);

  for (int jt = 0; jt < (SEQ / JSPLIT) / 64; jt++) {   // 8 epochs of 64 j
    const int j0 = jbase + jt * 64;

    // ---- K fragments + eid words straight from global (L2)
    F8 kf[4][2];
    unsigned ed[4];
#pragma unroll
    for (int c = 0; c < 4; c++) {
#pragma unroll
      for (int kc = 0; kc < 2; kc++)
        kf[c][kc].u4 = *(const uint4*)(kbase + (size_t)(j0 + c * 16 + lr) * HD + kc * 32 + lg * 8);
      ed[c] = erow[(j0 >> 2) + c * 4 + lg];
    }

    // ---- S^T = mfma(K, Q): sacc[c][r] = S[i=irow][j = j0 + c*16 + lg*4 + r]
    float4v sacc[4];
#pragma unroll
    for (int c = 0; c < 4; c++) sacc[c] = (float4v){0.f, 0.f, 0.f, 0.f};
#pragma unroll
    for (int kc = 0; kc < 2; kc++)
#pragma unroll
      for (int c = 0; c < 4; c++)
        sacc[c] = __builtin_amdgcn_mfma_f32_16x16x32_bf16(kf[c][kc].v, qf[kc].v, sacc[c], 0, 0, 0);

    // ---- edge bias + online softmax (all register / wave-local)
    float rmax = -1e30f;
#pragma unroll
    for (int c = 0; c < 4; c++) {
      const unsigned e = ed[c];
#pragma unroll
      for (int r = 0; r < 4; r++) {
        const float s = sacc[c][r] + tsl[wave][lr][(e >> (r * 8)) & 0xffu];
        sacc[c][r] = s;
        rmax = fmaxf(rmax, s);
      }
    }
    rmax = fmaxf(rmax, __shfl_xor(rmax, 16));
    rmax = fmaxf(rmax, __shfl_xor(rmax, 32));
    const float mnew = fmaxf(m_i, rmax);
    const float fct = exp2f(m_i - mnew);
    float rsum = 0.f;
#pragma unroll
    for (int c = 0; c < 4; c++) {
#pragma unroll
      for (int r = 0; r < 4; r++) {
        const float p_ = exp2f(sacc[c][r] - mnew);
        sacc[c][r] = p_;
        rsum += p_;
      }
    }
    rsum += __shfl_xor(rsum, 16);
    rsum += __shfl_xor(rsum, 32);
    l_i = l_i * fct + rsum;
    m_i = mnew;

    // ---- pack P into 16x16x16 A-fragments (registers)
    uint2 pa_[4];
#pragma unroll
    for (int c = 0; c < 4; c++) {
      pa_[c].x = cvtpk(sacc[c][0], sacc[c][1]);
      pa_[c].y = cvtpk(sacc[c][2], sacc[c][3]);
    }
    // rescale O: row of ao[db][rr] is i-local = lg*4+rr
    float fctv[4];
#pragma unroll
    for (int rr = 0; rr < 4; rr++) fctv[rr] = __shfl(fct, lg * 4 + rr);
#pragma unroll
    for (int db = 0; db < 4; db++)
#pragma unroll
      for (int rr = 0; rr < 4; rr++) ao[db][rr] *= fctv[rr];

    // ---- O += P * V: V B-frags (8B) straight from global (L2)
#pragma unroll
    for (int c = 0; c < 4; c++) {
#pragma unroll
      for (int db = 0; db < 4; db++) {
        uint2 vb = *(const uint2*)(vbase + (size_t)(db * 16 + lr) * SEQ + j0 + c * 16 + lg * 4);
        pv_mfma(ao[db], pa_[c], vb);
      }
    }
  }

  // ---- write partials (U bf16; m/l fp32, base-2 domain)
  {
    const size_t base = (((size_t)z * NHEAD + h) * SEQ + i0) * HD;
#pragma unroll
    for (int db = 0; db < 4; db++) {
#pragma unroll
      for (int rr = 0; rr < 4; rr++) {
        const int n = wave * 16 + lg * 4 + rr;
        Upart[base + (size_t)n * HD + db * 16 + lr] = f2bf(ao[db][rr]);
      }
    }
    if (lg == 0) {
      mpart[((size_t)z * NHEAD + h) * SEQ + irow] = m_i;
      lpart[((size_t)z * NHEAD + h) * SEQ + irow] = l_i;
    }
  }
}

// ---------------------------------------------------------------- K3: combine + out-projection
// 32x64-tile GEMM (BK=64, 512 blocks) out = AO * opwb^T + opb; AO combined on the fly
// from JSPLIT=4 bf16 partials; opwb pre-converted bf16. XCD X owns m-tiles [8X,8X+8).
__global__ __launch_bounds__(256) void combine_outproj(
    const u16* __restrict__ Upart, const float* __restrict__ mpart,
    const float* __restrict__ lpart, const u16* __restrict__ opwb,
    const float* __restrict__ opb, float* __restrict__ out)
{
  __shared__ u16 As[32][72];
  __shared__ u16 Bs[64][72];
  __shared__ float cww[JSPLIT][NHEAD][32];

  const int t = threadIdx.x;
  const int b = blockIdx.x;
  const int X = b & 7, jb = b >> 3;
  const int mt = X * 8 + (jb >> 3), nt = jb & 7;
  const int m0 = mt * 32, n0 = nt * 64;

  // combine weights per (h, local row): 8 heads x 32 rows = 256 -> one per thread
  {
    const int hh = t >> 5, nl = t & 31;
    const int gn = m0 + nl;
    float mz[JSPLIT], wz[JSPLIT];
    float M = -1e30f;
#pragma unroll
    for (int zz = 0; zz < JSPLIT; zz++) {
      mz[zz] = mpart[((size_t)zz * NHEAD + hh) * SEQ + gn];
      M = fmaxf(M, mz[zz]);
    }
    float Ls = 0.f;
#pragma unroll
    for (int zz = 0; zz < JSPLIT; zz++) {
      wz[zz] = exp2f(mz[zz] - M);
      Ls += wz[zz] * lpart[((size_t)zz * NHEAD + hh) * SEQ + gn];
    }
    const float inv = 1.0f / Ls;
#pragma unroll
    for (int zz = 0; zz < JSPLIT; zz++) cww[zz][hh][nl] = wz[zz] * inv;
  }
  __syncthreads();

  const int w = t >> 6, lane = t & 63, lr = lane & 15, lg = lane >> 4;
  const int arow = t >> 3, akb = (t & 7) * 8;     // A staging: 32 rows x 64 k
  const int brow = t >> 2, bkb = (t & 3) * 16;    // B staging: 64 rows x 64 k

  float4v acc[2];
#pragma unroll
  for (int mi = 0; mi < 2; mi++) acc[mi] = (float4v){0.f, 0.f, 0.f, 0.f};

  const u16* pw = opwb + (size_t)(n0 + brow) * EMB + bkb;

  int hcur = akb >> 6, dcur = akb & 63;
  uint4 ua[JSPLIT];
#pragma unroll
  for (int zz = 0; zz < JSPLIT; zz++)
    ua[zz] = *(const uint4*)(Upart + (((size_t)zz * NHEAD + hcur) * SEQ + m0 + arow) * HD + dcur);
  uint4 bb0 = *(const uint4*)pw, bb1 = *(const uint4*)(pw + 8);

  for (int k0 = 0; k0 < EMB; k0 += 64) {
    // combine -> bf16 A tile (8 elems/thread); B tile direct bf16 copy
    {
      float cc[8];
#pragma unroll
      for (int j = 0; j < 8; j++) cc[j] = 0.f;
#pragma unroll
      for (int zz = 0; zz < JSPLIT; zz++) {
        const float wgt = cww[zz][hcur][arow];
        F8 q0; q0.u4 = ua[zz];
#pragma unroll
        for (int j = 0; j < 8; j++) cc[j] += wgt * bf2f((u16)q0.us[j]);
      }
      float4 c0 = {cc[0], cc[1], cc[2], cc[3]}, c1 = {cc[4], cc[5], cc[6], cc[7]};
      *(uint4*)&As[arow][akb] = pk8(c0, c1);
      *(uint4*)&Bs[brow][bkb]     = bb0;
      *(uint4*)&Bs[brow][bkb + 8] = bb1;
    }
    __syncthreads();
    if (k0 + 64 < EMB) {                          // prefetch next K-tile
      const int e = k0 + 64 + akb;
      hcur = e >> 6; dcur = e & 63;
#pragma unroll
      for (int zz = 0; zz < JSPLIT; zz++)
        ua[zz] = *(const uint4*)(Upart + (((size_t)zz * NHEAD + hcur) * SEQ + m0 + arow) * HD + dcur);
      bb0 = *(const uint4*)(pw + k0 + 64);
      bb1 = *(const uint4*)(pw + k0 + 64 + 8);
    }
    F8 af[2][2], bf_[2];
#pragma unroll
    for (int kc = 0; kc < 2; kc++) {
#pragma unroll
      for (int mi = 0; mi < 2; mi++)
        af[mi][kc].u4 = *(const uint4*)&As[mi * 16 + lr][kc * 32 + lg * 8];
      bf_[kc].u4 = *(const uint4*)&Bs[w * 16 + lr][kc * 32 + lg * 8];
    }
#pragma unroll
    for (int kc = 0; kc < 2; kc++)
#pragma unroll
      for (int mi = 0; mi < 2; mi++)
        acc[mi] = __builtin_amdgcn_mfma_f32_16x16x32_bf16(af[mi][kc].v, bf_[kc].v, acc[mi], 0, 0, 0);
    __syncthreads();
  }

  const int n = n0 + w * 16 + lr;
  const float bias = opb[n];
#pragma unroll
  for (int mi = 0; mi < 2; mi++) {
    const int mb = m0 + mi * 16 + lg * 4;
#pragma unroll
    for (int r = 0; r < 4; r++)
      out[(size_t)(mb + r) * EMB + n] = acc[mi][r] + bias;
  }
}

// ---------------------------------------------------------------- launcher
extern "C" void kernel_launch(void* const* d_in, const int* in_sizes, int n_in,
                              void* d_out, int out_size, void* d_ws, size_t ws_size,
                              hipStream_t stream)
{
  const float* query = (const float*)d_in[0];
  const float* key_  = (const float*)d_in[1];
  const float* value = (const float*)d_in[2];
  const int*   eid   = (const int*)d_in[3];
  const float* ipw   = (const float*)d_in[4];
  const float* ipb   = (const float*)d_in[5];
  const float* opw   = (const float*)d_in[6];
  const float* opb   = (const float*)d_in[7];
  const float* ek    = (const float*)d_in[8];
  float* out = (float*)d_out;

  char* ws = (char*)d_ws;
  u16* Qs = (u16*)ws;              ws += (size_t)NHEAD * SEQ * HD * 2;
  u16* Kb = (u16*)ws;              ws += (size_t)NHEAD * SEQ * HD * 2;
  u16* Vb = (u16*)ws;              ws += (size_t)NHEAD * SEQ * HD * 2;     // transposed [h][d][j]
  unsigned* eidp = (unsigned*)ws;  ws += (size_t)SEQ * SEQ;                // u8-packed as u32
  u16* Upart = (u16*)ws;           ws += (size_t)JSPLIT * NHEAD * SEQ * HD * 2;  // bf16 partials
  float* mpart = (float*)ws;       ws += (size_t)JSPLIT * NHEAD * SEQ * 4;
  float* lpart = (float*)ws;       ws += (size_t)JSPLIT * NHEAD * SEQ * 4;
  u16* opwb = (u16*)ws;            ws += (size_t)EMB * EMB * 2;            // bf16 opw
  u16* EKb  = (u16*)ws;            ws += (size_t)16 * HD * 2;              // bf16 EK padded

  fused_prep_gemm<<<dim3(PREP_BLOCKS), dim3(256), 0, stream>>>(
      query, key_, value, ipw, ipb, eid, opw, ek, Qs, Kb, Vb, eidp, opwb, EKb);
  attn_kernel<<<dim3(SEQ / 64 * NHEAD * JSPLIT), dim3(256), 0, stream>>>(
      Qs, Kb, Vb, eidp, EKb, Upart, mpart, lpart);
  combine_outproj<<<dim3((SEQ / 32) * (EMB / 64)), dim3(256), 0, stream>>>(
      Upart, mpart, lpart, opwb, opb, out);
}

// Round 12
// 146.664 us; speedup vs baseline: 1.4345x; 1.4345x over previous
//
#include <hip/hip_runtime.h>
#include <hip/hip_bf16.h>

#define NHEAD 8
#define SEQ   2048
#define HD    64
#define EMB   512
#define NTYPE 10
#define JSPLIT 4

#define QKV_NT (3 * EMB / 64)              // 24 n-tiles
#define QKV_MT (SEQ / 64)                  // 32 m-tiles
#define QKV_BLOCKS (QKV_NT * QKV_MT)       // 768
#define PACK_BLOCKS (SEQ * SEQ / 4 / 256)  // 4096
#define OPW_BLOCKS (EMB * EMB / 8 / 256)   // 128
#define PREP_BLOCKS (QKV_BLOCKS + PACK_BLOCKS + OPW_BLOCKS + 1)

#define QSCALE 0.180336878f                // 0.125 * log2(e): exp2-domain softmax

typedef unsigned short u16;
typedef __attribute__((ext_vector_type(8))) short short8;
typedef __attribute__((ext_vector_type(4))) short short4v;
typedef __attribute__((ext_vector_type(4))) float float4v;

union F8 { short8 v; uint4 u4; u16 us[8]; };
union PB { uint2 u2; short4v s4; };

__device__ __forceinline__ float bf2f(u16 u){
  union { unsigned u; float f; } w; w.u = ((unsigned)u) << 16; return w.f;
}
__device__ __forceinline__ u16 f2bf(float f){
  union { float f; unsigned u; } w; w.f = f;
  unsigned u = w.u;
  u += 0x7fffu + ((u >> 16) & 1u);   // RNE
  return (u16)(u >> 16);
}
// HW v_cvt_pk_bf16_f32 (RNE)
__device__ __forceinline__ unsigned cvtpk(float lo, float hi){
  union { __hip_bfloat162 b; unsigned u; } w;
  w.b = __float22bfloat162_rn(float2{lo, hi});
  return w.u;
}
__device__ __forceinline__ uint4 pk8(float4 a, float4 b){
  uint4 p; p.x = cvtpk(a.x, a.y); p.y = cvtpk(a.z, a.w);
           p.z = cvtpk(b.x, b.y); p.w = cvtpk(b.z, b.w);
  return p;
}

// PV micro-op: ao += P(A-frag, regs) * V(B-frag, 4 bf16).
__device__ __forceinline__ void pv_mfma(float4v& ao, uint2 pa, uint2 vb){
#if __has_builtin(__builtin_amdgcn_mfma_f32_16x16x16bf16_1k)
  PB a; a.u2 = pa;
  PB b; b.u2 = vb;
  ao = __builtin_amdgcn_mfma_f32_16x16x16bf16_1k(a.s4, b.s4, ao, 0, 0, 0);
#else
  asm volatile("s_nop 1\n\tv_mfma_f32_16x16x16_bf16 %0, %1, %2, %0"
               : "+v"(ao) : "v"(pa), "v"(vb));
#endif
}

// ---------------------------------------------------------------- K1: QKV projection + eid pack + opw cvt + EK pad
// blocks [0,768): 64x64 GEMM, BK=64, reg-staged fp32->bf16, XCD-grouped (X owns 4 m-tiles).
// blocks [768, 4864): eid int32 -> u8 pack.
// blocks [4864, 4992): opw fp32 -> bf16.
// block 4992: EK -> bf16, zero-padded to 16 type rows.
__global__ __launch_bounds__(256) void fused_prep_gemm(
    const float* __restrict__ q, const float* __restrict__ k, const float* __restrict__ v,
    const float* __restrict__ ipw, const float* __restrict__ ipb, const int* __restrict__ eid,
    const float* __restrict__ opw, const float* __restrict__ ek,
    u16* __restrict__ Qs, u16* __restrict__ Kb, u16* __restrict__ Vb,
    unsigned* __restrict__ eidp, u16* __restrict__ opwb, u16* __restrict__ EKb)
{
  const int b = blockIdx.x;
  const int t = threadIdx.x;

  if (b >= QKV_BLOCKS) {
    if (b < QKV_BLOCKS + PACK_BLOCKS) {          // ---- eid pack
      const int i = (b - QKV_BLOCKS) * 256 + t;
      int4 vv = ((const int4*)eid)[i];
      eidp[i] = (unsigned)(vv.x & 0xff) | ((unsigned)(vv.y & 0xff) << 8) |
                ((unsigned)(vv.z & 0xff) << 16) | ((unsigned)(vv.w & 0xff) << 24);
    } else if (b < QKV_BLOCKS + PACK_BLOCKS + OPW_BLOCKS) {   // ---- opw -> bf16
      const int i = (b - QKV_BLOCKS - PACK_BLOCKS) * 256 + t;
      float4 a = *(const float4*)(opw + i * 8);
      float4 c = *(const float4*)(opw + i * 8 + 4);
      *(uint4*)(opwb + i * 8) = pk8(a, c);
    } else {                                     // ---- EK -> bf16, pad to 16 rows
      const int gi = t * 4;                      // 1024 = 16x64
      ushort4 pk;
      u16* pp = (u16*)&pk;
#pragma unroll
      for (int e = 0; e < 4; e++) {
        const int type = (gi + e) >> 6, d = (gi + e) & 63;
        pp[e] = f2bf(type < NTYPE ? ek[type * HD + d] : 0.f);
      }
      *(ushort4*)(EKb + gi) = pk;
    }
    return;
  }

  __shared__ u16 As[64][72];
  __shared__ u16 Bs[64][72];

  const int X = b & 7, jb = b >> 3;
  const int mt = X * 4 + (jb & 3), nt = jb >> 2;
  const int n0 = nt * 64, m0 = mt * 64;
  const int z = n0 >> 9;                       // 0=q,1=k,2=v
  const float* A = (z == 0) ? q : (z == 1) ? k : v;
  const float scale = (z == 0) ? QSCALE : 1.0f;

  const int w = t >> 6, lane = t & 63, lr = lane & 15, lg = lane >> 4;
  const int wm = w >> 1, wn = w & 1;
  const int srow = t >> 2, kb16 = (t & 3) * 16;

  float4v acc[2][2];
#pragma unroll
  for (int mi = 0; mi < 2; mi++)
#pragma unroll
    for (int ni = 0; ni < 2; ni++) acc[mi][ni] = (float4v){0.f, 0.f, 0.f, 0.f};

  const float* pa = A   + (size_t)(m0 + srow) * EMB + kb16;
  const float* pw = ipw + (size_t)(n0 + srow) * EMB + kb16;

  float4 a[4], bb[4];
#pragma unroll
  for (int j = 0; j < 4; j++) { a[j] = *(const float4*)(pa + j * 4); bb[j] = *(const float4*)(pw + j * 4); }

  for (int k0 = 0; k0 < EMB; k0 += 64) {
    *(uint4*)&As[srow][kb16]     = pk8(a[0], a[1]);
    *(uint4*)&As[srow][kb16 + 8] = pk8(a[2], a[3]);
    *(uint4*)&Bs[srow][kb16]     = pk8(bb[0], bb[1]);
    *(uint4*)&Bs[srow][kb16 + 8] = pk8(bb[2], bb[3]);
    __syncthreads();
    if (k0 + 64 < EMB) {                       // prefetch next K-tile
#pragma unroll
      for (int j = 0; j < 4; j++) {
        a[j]  = *(const float4*)(pa + k0 + 64 + j * 4);
        bb[j] = *(const float4*)(pw + k0 + 64 + j * 4);
      }
    }
    F8 af[2][2], bf_[2][2];
#pragma unroll
    for (int kc = 0; kc < 2; kc++) {
#pragma unroll
      for (int mi = 0; mi < 2; mi++)
        af[mi][kc].u4 = *(const uint4*)&As[wm * 32 + mi * 16 + lr][kc * 32 + lg * 8];
#pragma unroll
      for (int ni = 0; ni < 2; ni++)
        bf_[ni][kc].u4 = *(const uint4*)&Bs[wn * 32 + ni * 16 + lr][kc * 32 + lg * 8];
    }
#pragma unroll
    for (int kc = 0; kc < 2; kc++)
#pragma unroll
      for (int mi = 0; mi < 2; mi++)
#pragma unroll
        for (int ni = 0; ni < 2; ni++)
          acc[mi][ni] = __builtin_amdgcn_mfma_f32_16x16x32_bf16(af[mi][kc].v, bf_[ni][kc].v, acc[mi][ni], 0, 0, 0);
    __syncthreads();
  }

  u16* O = (z == 0) ? Qs : ((z == 1) ? Kb : Vb);
#pragma unroll
  for (int mi = 0; mi < 2; mi++) {
#pragma unroll
    for (int ni = 0; ni < 2; ni++) {
      const int n = n0 + wn * 32 + ni * 16 + lr;
      const int e = n & 511, h = e >> 6, d = e & 63;
      const float bias = ipb[n];
      const int mb = m0 + wm * 32 + mi * 16 + lg * 4;
      if (z < 2) {
#pragma unroll
        for (int r = 0; r < 4; r++)
          O[((size_t)h * SEQ + mb + r) * HD + d] = f2bf((acc[mi][ni][r] + bias) * scale);
      } else {
        ushort4 pk;
        pk.x = f2bf(acc[mi][ni][0] + bias); pk.y = f2bf(acc[mi][ni][1] + bias);
        pk.z = f2bf(acc[mi][ni][2] + bias); pk.w = f2bf(acc[mi][ni][3] + bias);
        *(ushort4*)(O + ((size_t)(h * HD + d)) * SEQ + mb) = pk;   // V^T layout [h][d][m]
      }
    }
  }
}

// ---------------------------------------------------------------- K2: flash attention with edge bias
// Round-8 base (K/V LDS staging + T14 reg-prefetch, 2 barriers/tile) with:
//  - PV from REGISTER P-fragments via 16x16x16 MFMA (no P LDS round-trip);
//  - V staged in fragment-native layout VF[bidx=c*4+db][lane] (67-uint2 padded rows)
//    so every PV b64 read is lane-consecutive (conflict-free);
//  - type scores via 2-MFMA trick into per-wave tsl.
// grid 1024 = 32 i x 8 h x 4 z, XCD-grouped (X owns 4 (h,z) pairs).
__global__ __launch_bounds__(256) void attn_kernel(
    const u16* __restrict__ Qs, const u16* __restrict__ Kb, const u16* __restrict__ Vb,
    const unsigned* __restrict__ eid32, const u16* __restrict__ EKb,
    u16* __restrict__ Upart, float* __restrict__ mpart, float* __restrict__ lpart)
{
  __shared__ u16 Kt[64][72];            // K tile [j][d]
  __shared__ uint2 VF[16 * 67];         // V fragments: [c*4+db][lane], padded stride 67
  __shared__ float tsl[4][16][18];      // per-wave type scores [i-local][type]

  const int t = threadIdx.x;
  const int wave = t >> 6, lane = t & 63, lr = lane & 15, lg = lane >> 4;
  const int bb_ = blockIdx.x;
  const int X = bb_ & 7, jj = bb_ >> 3;           // jj 0..127
  const int p = X * 4 + (jj >> 5);                // pair 0..31
  const int i0 = (jj & 31) * 64;
  const int h  = p >> 2;
  const int z  = p & 3;

  const int irow = i0 + wave * 16 + lr;           // this lane's Q row

  // Q fragments (B operand), held in regs
  F8 qf[2];
#pragma unroll
  for (int kc = 0; kc < 2; kc++)
    qf[kc].u4 = *(const uint4*)(Qs + ((size_t)h * SEQ + irow) * HD + kc * 32 + lg * 8);

  // type scores via MFMA: TS[i=lr][type=lg*4+r] (EK zero-padded to 16 rows)
  {
    float4v ts = (float4v){0.f, 0.f, 0.f, 0.f};
#pragma unroll
    for (int kc = 0; kc < 2; kc++) {
      F8 ekf; ekf.u4 = *(const uint4*)(EKb + lr * HD + kc * 32 + lg * 8);
      ts = __builtin_amdgcn_mfma_f32_16x16x32_bf16(ekf.v, qf[kc].v, ts, 0, 0, 0);
    }
    *(float2*)&tsl[wave][lr][lg * 4]     = float2{ts[0], ts[1]};
    *(float2*)&tsl[wave][lr][lg * 4 + 2] = float2{ts[2], ts[3]};
  }

  float4v ao[4];                        // ao[db][rr] = O[i=lg*4+rr][d=db*16+lr]
#pragma unroll
  for (int d = 0; d < 4; d++) ao[d] = (float4v){0.f, 0.f, 0.f, 0.f};
  float m_i = -1e30f, l_i = 0.f;        // own-row (i = irow) softmax state

  const int srow = t >> 2, sdc = (t & 3) * 16;
  // V staging target: thread's 16 elems are d=srow, j=[sdc,sdc+16) -> c = t&3,
  // db = srow>>4, lr' = srow&15, lg chunk per 4 j. VF slot = bidx*67 + lg*16 + lr'.
  const int vslot = ((t & 3) * 4 + (srow >> 4)) * 67 + (srow & 15);
  const int jbase = z * (SEQ / JSPLIT);
  const int NT = (SEQ / JSPLIT) / 64;   // 8
  const unsigned* erow = eid32 + (size_t)irow * (SEQ / 4);

  uint4 kp0, kp1, vp0, vp1;
  unsigned ed[4], edn[4];
  {
    const u16* kp = Kb + ((size_t)h * SEQ + jbase + srow) * HD + sdc;
    kp0 = *(const uint4*)kp; kp1 = *(const uint4*)(kp + 8);
    const u16* vp = Vb + ((size_t)(h * HD + srow)) * SEQ + jbase + sdc;
    vp0 = *(const uint4*)vp; vp1 = *(const uint4*)(vp + 8);
    *(uint4*)&Kt[srow][sdc] = kp0; *(uint4*)&Kt[srow][sdc + 8] = kp1;
    VF[vslot]      = uint2{vp0.x, vp0.y};
    VF[vslot + 16] = uint2{vp0.z, vp0.w};
    VF[vslot + 32] = uint2{vp1.x, vp1.y};
    VF[vslot + 48] = uint2{vp1.z, vp1.w};
    const int ej = jbase >> 2;
#pragma unroll
    for (int c = 0; c < 4; c++) ed[c] = erow[ej + c * 4 + lg];
  }

  for (int jt = 0; jt < NT; jt++) {
    __syncthreads();                               // tile jt staged (and tsl on jt==0)

    if (jt + 1 < NT) {                             // T14: issue next tile's loads
      const int jn = jbase + (jt + 1) * 64;
      const u16* kp = Kb + ((size_t)h * SEQ + jn + srow) * HD + sdc;
      kp0 = *(const uint4*)kp; kp1 = *(const uint4*)(kp + 8);
      const u16* vp = Vb + ((size_t)(h * HD + srow)) * SEQ + jn + sdc;
      vp0 = *(const uint4*)vp; vp1 = *(const uint4*)(vp + 8);
      const int ejn = jn >> 2;
#pragma unroll
      for (int c = 0; c < 4; c++) edn[c] = erow[ejn + c * 4 + lg];
    }

    // ---- S^T = mfma(K, Q): sacc[c][r] = S[i=irow][j = c*16 + lg*4 + r]
    float4v sacc[4];
#pragma unroll
    for (int c = 0; c < 4; c++) sacc[c] = (float4v){0.f, 0.f, 0.f, 0.f};
#pragma unroll
    for (int kc = 0; kc < 2; kc++) {
#pragma unroll
      for (int c = 0; c < 4; c++) {
        F8 kf; kf.u4 = *(const uint4*)&Kt[c * 16 + lr][kc * 32 + lg * 8];
        sacc[c] = __builtin_amdgcn_mfma_f32_16x16x32_bf16(kf.v, qf[kc].v, sacc[c], 0, 0, 0);
      }
    }

    // ---- edge bias + online softmax (register / wave-local)
    float rmax = -1e30f;
#pragma unroll
    for (int c = 0; c < 4; c++) {
      const unsigned e = ed[c];
#pragma unroll
      for (int r = 0; r < 4; r++) {
        const float s = sacc[c][r] + tsl[wave][lr][(e >> (r * 8)) & 0xffu];
        sacc[c][r] = s;
        rmax = fmaxf(rmax, s);
      }
    }
    rmax = fmaxf(rmax, __shfl_xor(rmax, 16));
    rmax = fmaxf(rmax, __shfl_xor(rmax, 32));
    const float mnew = fmaxf(m_i, rmax);
    const float fct = exp2f(m_i - mnew);
    float rsum = 0.f;
#pragma unroll
    for (int c = 0; c < 4; c++) {
#pragma unroll
      for (int r = 0; r < 4; r++) {
        const float p_ = exp2f(sacc[c][r] - mnew);
        sacc[c][r] = p_;
        rsum += p_;
      }
    }
    rsum += __shfl_xor(rsum, 16);
    rsum += __shfl_xor(rsum, 32);
    l_i = l_i * fct + rsum;
    m_i = mnew;

    // ---- pack P into 16x16x16 A-fragments (registers)
    uint2 pa_[4];
#pragma unroll
    for (int c = 0; c < 4; c++) {
      pa_[c].x = cvtpk(sacc[c][0], sacc[c][1]);
      pa_[c].y = cvtpk(sacc[c][2], sacc[c][3]);
    }
    // rescale O: row of ao[db][rr] is i-local = lg*4+rr
    float fctv[4];
#pragma unroll
    for (int rr = 0; rr < 4; rr++) fctv[rr] = __shfl(fct, lg * 4 + rr);
#pragma unroll
    for (int db = 0; db < 4; db++)
#pragma unroll
      for (int rr = 0; rr < 4; rr++) ao[db][rr] *= fctv[rr];

    // ---- O += P * V: V b64 reads lane-consecutive from VF (conflict-free)
#pragma unroll
    for (int c = 0; c < 4; c++) {
#pragma unroll
      for (int db = 0; db < 4; db++) {
        uint2 vb = VF[(c * 4 + db) * 67 + lane];
        pv_mfma(ao[db], pa_[c], vb);
      }
    }

    __syncthreads();                               // all waves done reading tile jt
    if (jt + 1 < NT) {                             // T14: write prefetched tile
      *(uint4*)&Kt[srow][sdc] = kp0; *(uint4*)&Kt[srow][sdc + 8] = kp1;
      VF[vslot]      = uint2{vp0.x, vp0.y};
      VF[vslot + 16] = uint2{vp0.z, vp0.w};
      VF[vslot + 32] = uint2{vp1.x, vp1.y};
      VF[vslot + 48] = uint2{vp1.z, vp1.w};
#pragma unroll
      for (int c = 0; c < 4; c++) ed[c] = edn[c];
    }
  }

  // ---- write partials (U bf16; m/l fp32, base-2 domain)
  {
    const size_t base = (((size_t)z * NHEAD + h) * SEQ + i0) * HD;
#pragma unroll
    for (int db = 0; db < 4; db++) {
#pragma unroll
      for (int rr = 0; rr < 4; rr++) {
        const int n = wave * 16 + lg * 4 + rr;
        Upart[base + (size_t)n * HD + db * 16 + lr] = f2bf(ao[db][rr]);
      }
    }
    if (lg == 0) {
      mpart[((size_t)z * NHEAD + h) * SEQ + irow] = m_i;
      lpart[((size_t)z * NHEAD + h) * SEQ + irow] = l_i;
    }
  }
}

// ---------------------------------------------------------------- K3: combine + out-projection
// 32x64-tile GEMM (BK=64, 512 blocks) out = AO * opwb^T + opb; AO combined on the fly
// from JSPLIT=4 bf16 partials; opwb pre-converted bf16. XCD X owns m-tiles [8X,8X+8).
__global__ __launch_bounds__(256) void combine_outproj(
    const u16* __restrict__ Upart, const float* __restrict__ mpart,
    const float* __restrict__ lpart, const u16* __restrict__ opwb,
    const float* __restrict__ opb, float* __restrict__ out)
{
  __shared__ u16 As[32][72];
  __shared__ u16 Bs[64][72];
  __shared__ float cww[JSPLIT][NHEAD][32];

  const int t = threadIdx.x;
  const int b = blockIdx.x;
  const int X = b & 7, jb = b >> 3;
  const int mt = X * 8 + (jb >> 3), nt = jb & 7;
  const int m0 = mt * 32, n0 = nt * 64;

  // combine weights per (h, local row): 8 heads x 32 rows = 256 -> one per thread
  {
    const int hh = t >> 5, nl = t & 31;
    const int gn = m0 + nl;
    float mz[JSPLIT], wz[JSPLIT];
    float M = -1e30f;
#pragma unroll
    for (int zz = 0; zz < JSPLIT; zz++) {
      mz[zz] = mpart[((size_t)zz * NHEAD + hh) * SEQ + gn];
      M = fmaxf(M, mz[zz]);
    }
    float Ls = 0.f;
#pragma unroll
    for (int zz = 0; zz < JSPLIT; zz++) {
      wz[zz] = exp2f(mz[zz] - M);
      Ls += wz[zz] * lpart[((size_t)zz * NHEAD + hh) * SEQ + gn];
    }
    const float inv = 1.0f / Ls;
#pragma unroll
    for (int zz = 0; zz < JSPLIT; zz++) cww[zz][hh][nl] = wz[zz] * inv;
  }
  __syncthreads();

  const int w = t >> 6, lane = t & 63, lr = lane & 15, lg = lane >> 4;
  const int arow = t >> 3, akb = (t & 7) * 8;     // A staging: 32 rows x 64 k
  const int brow = t >> 2, bkb = (t & 3) * 16;    // B staging: 64 rows x 64 k

  float4v acc[2];
#pragma unroll
  for (int mi = 0; mi < 2; mi++) acc[mi] = (float4v){0.f, 0.f, 0.f, 0.f};

  const u16* pw = opwb + (size_t)(n0 + brow) * EMB + bkb;

  int hcur = akb >> 6, dcur = akb & 63;
  uint4 ua[JSPLIT];
#pragma unroll
  for (int zz = 0; zz < JSPLIT; zz++)
    ua[zz] = *(const uint4*)(Upart + (((size_t)zz * NHEAD + hcur) * SEQ + m0 + arow) * HD + dcur);
  uint4 bb0 = *(const uint4*)pw, bb1 = *(const uint4*)(pw + 8);

  for (int k0 = 0; k0 < EMB; k0 += 64) {
    // combine -> bf16 A tile (8 elems/thread); B tile direct bf16 copy
    {
      float cc[8];
#pragma unroll
      for (int j = 0; j < 8; j++) cc[j] = 0.f;
#pragma unroll
      for (int zz = 0; zz < JSPLIT; zz++) {
        const float wgt = cww[zz][hcur][arow];
        F8 q0; q0.u4 = ua[zz];
#pragma unroll
        for (int j = 0; j < 8; j++) cc[j] += wgt * bf2f((u16)q0.us[j]);
      }
      float4 c0 = {cc[0], cc[1], cc[2], cc[3]}, c1 = {cc[4], cc[5], cc[6], cc[7]};
      *(uint4*)&As[arow][akb] = pk8(c0, c1);
      *(uint4*)&Bs[brow][bkb]     = bb0;
      *(uint4*)&Bs[brow][bkb + 8] = bb1;
    }
    __syncthreads();
    if (k0 + 64 < EMB) {                          // prefetch next K-tile
      const int e = k0 + 64 + akb;
      hcur = e >> 6; dcur = e & 63;
#pragma unroll
      for (int zz = 0; zz < JSPLIT; zz++)
        ua[zz] = *(const uint4*)(Upart + (((size_t)zz * NHEAD + hcur) * SEQ + m0 + arow) * HD + dcur);
      bb0 = *(const uint4*)(pw + k0 + 64);
      bb1 = *(const uint4*)(pw + k0 + 64 + 8);
    }
    F8 af[2][2], bf_[2];
#pragma unroll
    for (int kc = 0; kc < 2; kc++) {
#pragma unroll
      for (int mi = 0; mi < 2; mi++)
        af[mi][kc].u4 = *(const uint4*)&As[mi * 16 + lr][kc * 32 + lg * 8];
      bf_[kc].u4 = *(const uint4*)&Bs[w * 16 + lr][kc * 32 + lg * 8];
    }
#pragma unroll
    for (int kc = 0; kc < 2; kc++)
#pragma unroll
      for (int mi = 0; mi < 2; mi++)
        acc[mi] = __builtin_amdgcn_mfma_f32_16x16x32_bf16(af[mi][kc].v, bf_[kc].v, acc[mi], 0, 0, 0);
    __syncthreads();
  }

  const int n = n0 + w * 16 + lr;
  const float bias = opb[n];
#pragma unroll
  for (int mi = 0; mi < 2; mi++) {
    const int mb = m0 + mi * 16 + lg * 4;
#pragma unroll
    for (int r = 0; r < 4; r++)
      out[(size_t)(mb + r) * EMB + n] = acc[mi][r] + bias;
  }
}

// ---------------------------------------------------------------- launcher
extern "C" void kernel_launch(void* const* d_in, const int* in_sizes, int n_in,
                              void* d_out, int out_size, void* d_ws, size_t ws_size,
                              hipStream_t stream)
{
  const float* query = (const float*)d_in[0];
  const float* key_  = (const float*)d_in[1];
  const float* value = (const float*)d_in[2];
  const int*   eid   = (const int*)d_in[3];
  const float* ipw   = (const float*)d_in[4];
  const float* ipb   = (const float*)d_in[5];
  const float* opw   = (const float*)d_in[6];
  const float* opb   = (const float*)d_in[7];
  const float* ek    = (const float*)d_in[8];
  float* out = (float*)d_out;

  char* ws = (char*)d_ws;
  u16* Qs = (u16*)ws;              ws += (size_t)NHEAD * SEQ * HD * 2;
  u16* Kb = (u16*)ws;              ws += (size_t)NHEAD * SEQ * HD * 2;
  u16* Vb = (u16*)ws;              ws += (size_t)NHEAD * SEQ * HD * 2;     // transposed [h][d][j]
  unsigned* eidp = (unsigned*)ws;  ws += (size_t)SEQ * SEQ;                // u8-packed as u32
  u16* Upart = (u16*)ws;           ws += (size_t)JSPLIT * NHEAD * SEQ * HD * 2;  // bf16 partials
  float* mpart = (float*)ws;       ws += (size_t)JSPLIT * NHEAD * SEQ * 4;
  float* lpart = (float*)ws;       ws += (size_t)JSPLIT * NHEAD * SEQ * 4;
  u16* opwb = (u16*)ws;            ws += (size_t)EMB * EMB * 2;            // bf16 opw
  u16* EKb  = (u16*)ws;            ws += (size_t)16 * HD * 2;              // bf16 EK padded

  fused_prep_gemm<<<dim3(PREP_BLOCKS), dim3(256), 0, stream>>>(
      query, key_, value, ipw, ipb, eid, opw, ek, Qs, Kb, Vb, eidp, opwb, EKb);
  attn_kernel<<<dim3(SEQ / 64 * NHEAD * JSPLIT), dim3(256), 0, stream>>>(
      Qs, Kb, Vb, eidp, EKb, Upart, mpart, lpart);
  combine_outproj<<<dim3((SEQ / 32) * (EMB / 64)), dim3(256), 0, stream>>>(
      Upart, mpart, lpart, opwb, opb, out);
}